// Round 5
// baseline (259.408 us; speedup 1.0000x reference)
//
#include <hip/hip_runtime.h>
#include <hip/hip_bf16.h>
#include <math.h>

#define HID 64
#define NLAYERS 8
#define NTH 256
#define SF 8   // 16-sample fragments per wave => 128 samples/wave

typedef __attribute__((ext_vector_type(8))) short bf16x8;
typedef __attribute__((ext_vector_type(4))) float f32x4;
typedef __attribute__((ext_vector_type(4))) unsigned int u32x4;

// ws layout (floats): [0,65536)            A2/A3 fragments ushort[32][4096]
//                     [65536,65536+81920)  P64: per slot 5 regions of 1024 floats
//                        which==0: A1 frags as ushort[2048] (mf=0..3, ks=0)
//                        which==1: b1 bias in D-frag order (f32)
//                        which==2: b2 bias (f32)   which==3: b3 bias (f32)
//                        which==4: A4 frags as ushort[1024] (ks=0,1), rest unused
//                     [147456,147472)      b4 passive-component scalars
#define WS_P64_F 65536
#define WS_B4_F  (65536 + 81920)

__device__ __forceinline__ unsigned short f2bf(float f) {
    return __builtin_bit_cast(unsigned short, (__bf16)f);
}

// Pack two f32 -> one u32 of two bf16 (lo = a, hi = b) with round-half-away:
// +0x8000 then take top 16 bits via a single v_perm_b32 (CK's bf16-pack idiom).
// Builtins only - no inline asm (round-4 NaN came from the asm cvt path).
__device__ __forceinline__ unsigned int pk2(float a, float b) {
    const unsigned ua = __builtin_bit_cast(unsigned, a) + 0x8000u;
    const unsigned ub = __builtin_bit_cast(unsigned, b) + 0x8000u;
    return __builtin_amdgcn_perm(ub, ua, 0x07060302u);  // {ub.hi16, ua.hi16}
}

// relu + f32->bf16 pack for a D-fragment pair
__device__ __forceinline__ bf16x8 packR(f32x4 a, f32x4 b) {
    u32x4 o;
    o[0] = pk2(fmaxf(a[0], 0.f), fmaxf(a[1], 0.f));
    o[1] = pk2(fmaxf(a[2], 0.f), fmaxf(a[3], 0.f));
    o[2] = pk2(fmaxf(b[0], 0.f), fmaxf(b[1], 0.f));
    o[3] = pk2(fmaxf(b[2], 0.f), fmaxf(b[3], 0.f));
    return __builtin_bit_cast(bf16x8, o);
}

// One block per (layer, net). A-frag K-permutation k(ks,g,e)=16*(2ks+(e>>2))+4g+(e&3)
// makes layer n's D-layout directly consumable as layer n+1's B-operand.
__global__ void prepack_kernel(
    const float* __restrict__ s_w1, const float* __restrict__ s_b1,
    const float* __restrict__ s_w2, const float* __restrict__ s_b2,
    const float* __restrict__ s_w3, const float* __restrict__ s_b3,
    const float* __restrict__ s_w4, const float* __restrict__ s_b4,
    const float* __restrict__ t_w1, const float* __restrict__ t_b1,
    const float* __restrict__ t_w2, const float* __restrict__ t_b2,
    const float* __restrict__ t_w3, const float* __restrict__ t_b3,
    const float* __restrict__ t_w4, const float* __restrict__ t_b4,
    float* __restrict__ ws) {
    const int slot = blockIdx.x;            // l*2 + net
    const int l = slot >> 1, net = slot & 1;
    const int act = l & 1, pass = act ^ 1;
    const float* w1 = (net ? t_w1 : s_w1) + l * HID * 2;
    const float* b1 = (net ? t_b1 : s_b1) + l * HID;
    const float* w2 = (net ? t_w2 : s_w2) + l * HID * HID;
    const float* b2 = (net ? t_b2 : s_b2) + l * HID;
    const float* w3 = (net ? t_w3 : s_w3) + l * HID * HID;
    const float* b3 = (net ? t_b3 : s_b3) + l * HID;
    const float* w4 = (net ? t_w4 : s_w4) + l * 2 * HID;
    const float* b4 = (net ? t_b4 : s_b4) + l * 2;

    unsigned short* Aall = reinterpret_cast<unsigned short*>(ws);
    float* P64 = ws + WS_P64_F;
    float* B4P = ws + WS_B4_F;

    // A-operand fragments for the two 64x64 matmuls (W2, W3)
    for (int mat = 0; mat < 2; ++mat) {
        const float* W = mat ? w3 : w2;
        unsigned short* dst = Aall + (slot * 2 + mat) * 4096;
        for (int idx = threadIdx.x; idx < 4096; idx += NTH) {
            const int e = idx & 7, lane = (idx >> 3) & 63, fr = idx >> 9;
            const int ks = fr & 1, mf = fr >> 1;
            const int j = 16 * mf + (lane & 15);                       // out row
            const int k = 16 * (2 * ks + (e >> 2)) + 4 * (lane >> 4) + (e & 3);
            dst[idx] = f2bf(W[j * HID + k]);
        }
    }
    // which==0: A1 fragments (rank-1 layer 1; only k_phys==0 is nonzero -> ks=0, e=0, g=0)
    {
        unsigned short* dst = reinterpret_cast<unsigned short*>(P64 + (slot * 5 + 0) * 1024);
        for (int idx = threadIdx.x; idx < 2048; idx += NTH) {
            const int e = idx & 7, lane = (idx >> 3) & 63, mf = idx >> 9;
            const int j = 16 * mf + (lane & 15);
            const float v = (e == 0 && (lane >> 4) == 0) ? w1[2 * j + act] : 0.f;
            dst[idx] = f2bf(v);
        }
    }
    // which==1..3: bias fragments in D-layout order (f32)
    for (int which = 1; which <= 3; ++which) {
        float* dst = P64 + (slot * 5 + which) * 1024;
        const float* B = (which == 1) ? b1 : (which == 2) ? b2 : b3;
        for (int idx = threadIdx.x; idx < 1024; idx += NTH) {
            const int r = idx & 3, lane = (idx >> 2) & 63, f = idx >> 8;
            const int j = 16 * f + 4 * (lane >> 4) + r;
            dst[idx] = B[j];
        }
    }
    // which==4: A4 fragments (W4 passive row in A row 0, rows 1..15 zero)
    {
        unsigned short* dst = reinterpret_cast<unsigned short*>(P64 + (slot * 5 + 4) * 1024);
        for (int idx = threadIdx.x; idx < 1024; idx += NTH) {
            const int e = idx & 7, lane = (idx >> 3) & 63, ks = idx >> 9;
            const int k = 16 * (2 * ks + (e >> 2)) + 4 * (lane >> 4) + (e & 3);
            const float v = ((lane & 15) == 0) ? w4[pass * HID + k] : 0.f;
            dst[idx] = f2bf(v);
        }
    }
    if (threadIdx.x == 0) B4P[slot] = b4[pass];
}

__global__ __launch_bounds__(NTH) void nvp_mfma_kernel(
    const float* __restrict__ x, const float* __restrict__ ws,
    float* __restrict__ out, int n) {
    const int lane = threadIdx.x & 63;
    const int wid = (blockIdx.x * NTH + threadIdx.x) >> 6;
    const int c = lane & 15, g = lane >> 4;
    const long base = (long)wid * (16 * SF);
    if (base >= n) return;

    const unsigned short* Aall = reinterpret_cast<const unsigned short*>(ws);
    const float* P64 = ws + WS_P64_F;
    const float* B4P = ws + WS_B4_F;

    float y0[SF], y1[SF], ld[SF];
#pragma unroll
    for (int sf = 0; sf < SF; ++sf) {
        const float2 xv = reinterpret_cast<const float2*>(x)[base + 16 * sf + c];
        y0[sf] = xv.x; y1[sf] = xv.y; ld[sf] = 0.f;
    }

    for (int l = 0; l < NLAYERS; ++l) {
        const int act = l & 1;
        float sv[SF], tv[SF];

        // bf16(xa) per sf, hoisted: both nets consume the same active input.
        // Integer round-half-away + shift; builtins only.
        unsigned short xs[SF];
#pragma unroll
        for (int sf = 0; sf < SF; ++sf) {
            const float xa = act ? y1[sf] : y0[sf];
            xs[sf] = (unsigned short)((__builtin_bit_cast(unsigned, xa) + 0x8000u) >> 16);
        }

#pragma unroll
        for (int net = 0; net < 2; ++net) {
            const int slot = l * 2 + net;
            const float* PB = P64 + slot * 5 * 1024;
            const unsigned short* A1p = reinterpret_cast<const unsigned short*>(PB);
            const unsigned short* A4p = reinterpret_cast<const unsigned short*>(PB + 4 * 1024);
            const unsigned short* A2 = Aall + (slot * 2 + 0) * 4096;
            const unsigned short* A3 = Aall + (slot * 2 + 1) * 4096;

            // ---- phase A weights: A1, b1, A2, b2 (held in registers) ----
            bf16x8 a1[4], a2[8];
            f32x4 c1[4], c2[4];
#pragma unroll
            for (int mf = 0; mf < 4; ++mf) {
                a1[mf] = *reinterpret_cast<const bf16x8*>(A1p + (mf * 64 + lane) * 8);
                c1[mf] = *reinterpret_cast<const f32x4*>(PB + 1 * 1024 + (mf * 64 + lane) * 4);
                c2[mf] = *reinterpret_cast<const f32x4*>(PB + 2 * 1024 + (mf * 64 + lane) * 4);
            }
#pragma unroll
            for (int fr = 0; fr < 8; ++fr)
                a2[fr] = *reinterpret_cast<const bf16x8*>(A2 + (fr * 64 + lane) * 8);

            bf16x8 bfr[SF][2];
#pragma unroll
            for (int sf = 0; sf < SF; ++sf) {
                // B1 frag: bf16(xa) at k_phys==0 (element 0, lanes g==0), zeros elsewhere
                bf16x8 b1f = (bf16x8)0;
                b1f[0] = (g == 0) ? (short)xs[sf] : (short)0;
                f32x4 acc[4];
                // layer 1: rank-1 MFMA, bias as C-in (K slots 1..31 of A are zero)
#pragma unroll
                for (int mf = 0; mf < 4; ++mf)
                    acc[mf] = __builtin_amdgcn_mfma_f32_16x16x32_bf16(a1[mf], b1f, c1[mf], 0, 0, 0);
                bf16x8 bb0 = packR(acc[0], acc[1]);
                bf16x8 bb1 = packR(acc[2], acc[3]);
                // layer 2
#pragma unroll
                for (int mf = 0; mf < 4; ++mf) {
                    f32x4 t0 = __builtin_amdgcn_mfma_f32_16x16x32_bf16(a2[2 * mf + 0], bb0, c2[mf], 0, 0, 0);
                    acc[mf]  = __builtin_amdgcn_mfma_f32_16x16x32_bf16(a2[2 * mf + 1], bb1, t0, 0, 0, 0);
                }
                bfr[sf][0] = packR(acc[0], acc[1]);
                bfr[sf][1] = packR(acc[2], acc[3]);
            }

            // ---- phase B weights: A3, b3, A4, b4 ----
            bf16x8 a3[8], a4[2];
            f32x4 c3[4];
#pragma unroll
            for (int fr = 0; fr < 8; ++fr)
                a3[fr] = *reinterpret_cast<const bf16x8*>(A3 + (fr * 64 + lane) * 8);
#pragma unroll
            for (int mf = 0; mf < 4; ++mf)
                c3[mf] = *reinterpret_cast<const f32x4*>(PB + 3 * 1024 + (mf * 64 + lane) * 4);
            a4[0] = *reinterpret_cast<const bf16x8*>(A4p + (0 * 64 + lane) * 8);
            a4[1] = *reinterpret_cast<const bf16x8*>(A4p + (1 * 64 + lane) * 8);
            const float b4v = B4P[slot];

#pragma unroll
            for (int sf = 0; sf < SF; ++sf) {
                f32x4 acc[4];
                // layer 3
#pragma unroll
                for (int mf = 0; mf < 4; ++mf) {
                    f32x4 t0 = __builtin_amdgcn_mfma_f32_16x16x32_bf16(a3[2 * mf + 0], bfr[sf][0], c3[mf], 0, 0, 0);
                    acc[mf]  = __builtin_amdgcn_mfma_f32_16x16x32_bf16(a3[2 * mf + 1], bfr[sf][1], t0, 0, 0, 0);
                }
                bf16x8 bb0 = packR(acc[0], acc[1]);
                bf16x8 bb1 = packR(acc[2], acc[3]);
                // layer 4: W4 row dot via MFMA row 0, then broadcast from lane c
                f32x4 z = {0.f, 0.f, 0.f, 0.f};
                f32x4 d4 = __builtin_amdgcn_mfma_f32_16x16x32_bf16(a4[0], bb0, z, 0, 0, 0);
                d4 = __builtin_amdgcn_mfma_f32_16x16x32_bf16(a4[1], bb1, d4, 0, 0, 0);
                float p = __builtin_bit_cast(float,
                            __builtin_amdgcn_ds_bpermute(c * 4, __builtin_bit_cast(int, d4[0])));
                p += b4v;
                if (net == 0) sv[sf] = p; else tv[sf] = p;
            }
        }
        // ---- coupling update ----
#pragma unroll
        for (int sf = 0; sf < SF; ++sf) {
            const float e2 = __expf(2.f * sv[sf]);
            const float s = 1.f - 2.f / (e2 + 1.f);      // tanh(sv)
            const float es = __expf(s);
            if (act) y0[sf] = fmaf(y0[sf], es, tv[sf]);
            else     y1[sf] = fmaf(y1[sf], es, tv[sf]);
            ld[sf] += s;
        }
    }

    if (g == 0) {   // 4 lane-groups hold identical results; group 0 writes
#pragma unroll
        for (int sf = 0; sf < SF; ++sf) {
            const long sid = base + 16 * sf + c;
            reinterpret_cast<float2*>(out)[sid] = make_float2(y0[sf], y1[sf]);
            out[2 * (long)n + sid] = ld[sf];
        }
    }
}

extern "C" void kernel_launch(void* const* d_in, const int* in_sizes, int n_in,
                              void* d_out, int out_size, void* d_ws, size_t ws_size,
                              hipStream_t stream) {
    const float* x = (const float*)d_in[0];
    float* ws = (float*)d_ws;

    prepack_kernel<<<16, NTH, 0, stream>>>(
        (const float*)d_in[1],  (const float*)d_in[2],  (const float*)d_in[3],
        (const float*)d_in[4],  (const float*)d_in[5],  (const float*)d_in[6],
        (const float*)d_in[7],  (const float*)d_in[8],  (const float*)d_in[9],
        (const float*)d_in[10], (const float*)d_in[11], (const float*)d_in[12],
        (const float*)d_in[13], (const float*)d_in[14], (const float*)d_in[15],
        (const float*)d_in[16], ws);

    const int n = in_sizes[0] / 2;                        // x is (N, 2)
    const int samples_per_block = (NTH / 64) * 16 * SF;   // 512
    const int blocks = (n + samples_per_block - 1) / samples_per_block;

    nvp_mfma_kernel<<<blocks, NTH, 0, stream>>>(x, ws, (float*)d_out, n);
}

// Round 6
// 209.354 us; speedup vs baseline: 1.2391x; 1.2391x over previous
//
#include <hip/hip_runtime.h>
#include <hip/hip_bf16.h>
#include <math.h>

#define HID 64
#define NLAYERS 8
#define NTH 512        // 8 waves/block; 2 blocks/CU (LDS 48KB) -> 16 waves/CU
#define PRE_NTH 256
#define SF 8           // 16-sample fragments per wave => 128 samples/wave

// per-slot weight blob, ushort units (24576 B total, staged to LDS)
#define SLOT_US 12288
#define A1_US 0        // 2048 ushort
#define A2_US 2048     // 4096 ushort
#define A3_US 6144     // 4096 ushort
#define A4_US 10240    // 1024 ushort + 1024 pad
// float-unit offsets in ws
#define WS_BIAS_F 98304              // 16 slots * 6144 floats of blobs before this
#define WS_B4_F   (98304 + 16*3072)  // = 147456

typedef __attribute__((ext_vector_type(8))) short bf16x8;
typedef __attribute__((ext_vector_type(8))) __bf16 bf16v8;
typedef __attribute__((ext_vector_type(4))) float f32x4;

__device__ __forceinline__ unsigned short f2bf(float f) {
    return __builtin_bit_cast(unsigned short, (__bf16)f);
}

// relu + f32->bf16 pack; scalar __bf16 casts compile to v_cvt_pk_bf16_f32
// (round-5 lesson: hand-written packs are slower; keep the round-3 form).
__device__ __forceinline__ bf16x8 packR(f32x4 a, f32x4 b) {
    bf16v8 t;
    t[0] = (__bf16)fmaxf(a[0], 0.f);
    t[1] = (__bf16)fmaxf(a[1], 0.f);
    t[2] = (__bf16)fmaxf(a[2], 0.f);
    t[3] = (__bf16)fmaxf(a[3], 0.f);
    t[4] = (__bf16)fmaxf(b[0], 0.f);
    t[5] = (__bf16)fmaxf(b[1], 0.f);
    t[6] = (__bf16)fmaxf(b[2], 0.f);
    t[7] = (__bf16)fmaxf(b[3], 0.f);
    return __builtin_bit_cast(bf16x8, t);
}

// DMA one 16B chunk per lane: global -> LDS (wave-uniform LDS base + lane*16).
__device__ __forceinline__ void gload16(const unsigned short* g, unsigned short* l) {
    __builtin_amdgcn_global_load_lds(
        (const __attribute__((address_space(1))) unsigned int*)g,
        (__attribute__((address_space(3))) unsigned int*)l, 16, 0, 0);
}

// Stage one 24576B slot blob: 8 waves x 3 rounds x 64 lanes x 16B.
__device__ __forceinline__ void stage(unsigned short* lds, const unsigned short* gsrc, int tid) {
    const int lane = tid & 63, wv = tid >> 6;
#pragma unroll
    for (int r = 0; r < 3; ++r) {
        const int chunk = r * 512 + wv * 64;             // in 16B units
        gload16(gsrc + (chunk + lane) * 8, lds + chunk * 8);
    }
}

// One block per (layer, net) slot. A-frag K-permutation
// k(ks,g,e)=16*(2ks+(e>>2))+4g+(e&3) makes layer n's D-layout directly
// consumable as layer n+1's B-operand.
__global__ void prepack_kernel(
    const float* __restrict__ s_w1, const float* __restrict__ s_b1,
    const float* __restrict__ s_w2, const float* __restrict__ s_b2,
    const float* __restrict__ s_w3, const float* __restrict__ s_b3,
    const float* __restrict__ s_w4, const float* __restrict__ s_b4,
    const float* __restrict__ t_w1, const float* __restrict__ t_b1,
    const float* __restrict__ t_w2, const float* __restrict__ t_b2,
    const float* __restrict__ t_w3, const float* __restrict__ t_b3,
    const float* __restrict__ t_w4, const float* __restrict__ t_b4,
    float* __restrict__ ws) {
    const int slot = blockIdx.x;            // l*2 + net
    const int l = slot >> 1, net = slot & 1;
    const int act = l & 1, pass = act ^ 1;
    const float* w1 = (net ? t_w1 : s_w1) + l * HID * 2;
    const float* b1 = (net ? t_b1 : s_b1) + l * HID;
    const float* w2 = (net ? t_w2 : s_w2) + l * HID * HID;
    const float* b2 = (net ? t_b2 : s_b2) + l * HID;
    const float* w3 = (net ? t_w3 : s_w3) + l * HID * HID;
    const float* b3 = (net ? t_b3 : s_b3) + l * HID;
    const float* w4 = (net ? t_w4 : s_w4) + l * 2 * HID;
    const float* b4 = (net ? t_b4 : s_b4) + l * 2;

    unsigned short* blob = reinterpret_cast<unsigned short*>(ws) + slot * SLOT_US;

    // A1: rank-1 layer-1 fragments (only k_phys==0 nonzero -> e==0, g==0)
    for (int idx = threadIdx.x; idx < 2048; idx += PRE_NTH) {
        const int e = idx & 7, lane = (idx >> 3) & 63, mf = idx >> 9;
        const int j = 16 * mf + (lane & 15);
        blob[A1_US + idx] = f2bf((e == 0 && (lane >> 4) == 0) ? w1[2 * j + act] : 0.f);
    }
    // A2 / A3: 64x64 matmul fragments
    for (int mat = 0; mat < 2; ++mat) {
        const float* W = mat ? w3 : w2;
        unsigned short* dst = blob + (mat ? A3_US : A2_US);
        for (int idx = threadIdx.x; idx < 4096; idx += PRE_NTH) {
            const int e = idx & 7, lane = (idx >> 3) & 63, fr = idx >> 9;
            const int ks = fr & 1, mf = fr >> 1;
            const int j = 16 * mf + (lane & 15);
            const int k = 16 * (2 * ks + (e >> 2)) + 4 * (lane >> 4) + (e & 3);
            dst[idx] = f2bf(W[j * HID + k]);
        }
    }
    // A4: W4 passive row in A row 0, rows 1..15 zero
    for (int idx = threadIdx.x; idx < 1024; idx += PRE_NTH) {
        const int e = idx & 7, lane = (idx >> 3) & 63, ks = idx >> 9;
        const int k = 16 * (2 * ks + (e >> 2)) + 4 * (lane >> 4) + (e & 3);
        blob[A4_US + idx] = f2bf(((lane & 15) == 0) ? w4[pass * HID + k] : 0.f);
    }
    // biases b1,b2,b3 in D-fragment order (f32), kept in global (small)
    float* BP = ws + WS_BIAS_F + slot * 3072;
    for (int which = 0; which < 3; ++which) {
        const float* B = (which == 0) ? b1 : (which == 1) ? b2 : b3;
        for (int idx = threadIdx.x; idx < 1024; idx += PRE_NTH) {
            const int r = idx & 3, lane = (idx >> 2) & 63, f = idx >> 8;
            const int j = 16 * f + 4 * (lane >> 4) + r;
            BP[which * 1024 + idx] = B[j];
        }
    }
    if (threadIdx.x == 0) ws[WS_B4_F + slot] = b4[pass];
}

__global__ __launch_bounds__(NTH) void nvp_mfma_kernel(
    const float* __restrict__ x, const float* __restrict__ ws,
    float* __restrict__ out, int n) {
    __shared__ __align__(16) unsigned short smem[2 * SLOT_US];  // 48 KB double buffer
    const int tid = threadIdx.x;
    const int lane = tid & 63, wv = tid >> 6;
    const int c = lane & 15, g = lane >> 4;
    const int wid = blockIdx.x * (NTH / 64) + wv;
    long base = (long)wid * (16 * SF);
    const bool live = base < n;
    if (!live) base = 0;   // keep barrier participation uniform; skip writes later

    const unsigned short* wsu = reinterpret_cast<const unsigned short*>(ws);

    float y0[SF], y1[SF], ld[SF];
#pragma unroll
    for (int sf = 0; sf < SF; ++sf) {
        const float2 xv = reinterpret_cast<const float2*>(x)[base + 16 * sf + c];
        y0[sf] = xv.x; y1[sf] = xv.y; ld[sf] = 0.f;
    }

    // prologue: stage slot 0
    stage(smem, wsu, tid);

    float sv[SF], tv[SF];
    unsigned short xs[SF];

    for (int slot = 0; slot < 2 * NLAYERS; ++slot) {
        const int net = slot & 1;
        const int act = (slot >> 1) & 1;

        // staged data for this slot is ready after this barrier (vmcnt drained);
        // also closes all waves' reads of the buffer we stage into below.
        __syncthreads();
        if (slot < 2 * NLAYERS - 1)
            stage(smem + ((slot + 1) & 1) * SLOT_US, wsu + (slot + 1) * SLOT_US, tid);

        const unsigned short* SB = smem + (slot & 1) * SLOT_US;
        const float* BP = ws + WS_BIAS_F + slot * 3072;

        if (net == 0) {   // both nets consume the same active input
#pragma unroll
            for (int sf = 0; sf < SF; ++sf) {
                const float xa = act ? y1[sf] : y0[sf];
                xs[sf] = (unsigned short)((__builtin_bit_cast(unsigned, xa) + 0x8000u) >> 16);
            }
        }

        // ---- phase A weights: A1 (LDS), b1, b2 (global), A2 (LDS) ----
        bf16x8 a1[4], a2[8];
        f32x4 c1v[4], c2v[4];
#pragma unroll
        for (int mf = 0; mf < 4; ++mf) {
            a1[mf] = *reinterpret_cast<const bf16x8*>(SB + A1_US + (mf * 64 + lane) * 8);
            c1v[mf] = *reinterpret_cast<const f32x4*>(BP + 0 * 1024 + (mf * 64 + lane) * 4);
            c2v[mf] = *reinterpret_cast<const f32x4*>(BP + 1 * 1024 + (mf * 64 + lane) * 4);
        }
#pragma unroll
        for (int fr = 0; fr < 8; ++fr)
            a2[fr] = *reinterpret_cast<const bf16x8*>(SB + A2_US + (fr * 64 + lane) * 8);

        bf16x8 bfr[SF][2];
#pragma unroll
        for (int sf = 0; sf < SF; ++sf) {
            // B1 frag: bf16(xa) at k_phys==0 (element 0, lanes g==0), zeros elsewhere
            bf16x8 b1f = (bf16x8)0;
            b1f[0] = (g == 0) ? (short)xs[sf] : (short)0;
            f32x4 acc[4];
            // layer 1: rank-1 MFMA, bias as C-in
#pragma unroll
            for (int mf = 0; mf < 4; ++mf)
                acc[mf] = __builtin_amdgcn_mfma_f32_16x16x32_bf16(a1[mf], b1f, c1v[mf], 0, 0, 0);
            bf16x8 bb0 = packR(acc[0], acc[1]);
            bf16x8 bb1 = packR(acc[2], acc[3]);
            // layer 2
#pragma unroll
            for (int mf = 0; mf < 4; ++mf) {
                f32x4 t0 = __builtin_amdgcn_mfma_f32_16x16x32_bf16(a2[2 * mf + 0], bb0, c2v[mf], 0, 0, 0);
                acc[mf]  = __builtin_amdgcn_mfma_f32_16x16x32_bf16(a2[2 * mf + 1], bb1, t0, 0, 0, 0);
            }
            bfr[sf][0] = packR(acc[0], acc[1]);
            bfr[sf][1] = packR(acc[2], acc[3]);
        }

        // ---- phase B weights: A3 (LDS), b3 (global), A4 (LDS), b4 ----
        bf16x8 a3[8], a4[2];
        f32x4 c3v[4];
#pragma unroll
        for (int fr = 0; fr < 8; ++fr)
            a3[fr] = *reinterpret_cast<const bf16x8*>(SB + A3_US + (fr * 64 + lane) * 8);
#pragma unroll
        for (int mf = 0; mf < 4; ++mf)
            c3v[mf] = *reinterpret_cast<const f32x4*>(BP + 2 * 1024 + (mf * 64 + lane) * 4);
        a4[0] = *reinterpret_cast<const bf16x8*>(SB + A4_US + (0 * 64 + lane) * 8);
        a4[1] = *reinterpret_cast<const bf16x8*>(SB + A4_US + (1 * 64 + lane) * 8);
        const float b4v = ws[WS_B4_F + slot];

#pragma unroll
        for (int sf = 0; sf < SF; ++sf) {
            f32x4 acc[4];
            // layer 3
#pragma unroll
            for (int mf = 0; mf < 4; ++mf) {
                f32x4 t0 = __builtin_amdgcn_mfma_f32_16x16x32_bf16(a3[2 * mf + 0], bfr[sf][0], c3v[mf], 0, 0, 0);
                acc[mf]  = __builtin_amdgcn_mfma_f32_16x16x32_bf16(a3[2 * mf + 1], bfr[sf][1], t0, 0, 0, 0);
            }
            bf16x8 bb0 = packR(acc[0], acc[1]);
            bf16x8 bb1 = packR(acc[2], acc[3]);
            // layer 4: W4 row dot via MFMA row 0, then broadcast from lane c
            f32x4 z = {0.f, 0.f, 0.f, 0.f};
            f32x4 d4 = __builtin_amdgcn_mfma_f32_16x16x32_bf16(a4[0], bb0, z, 0, 0, 0);
            d4 = __builtin_amdgcn_mfma_f32_16x16x32_bf16(a4[1], bb1, d4, 0, 0, 0);
            float p = __builtin_bit_cast(float,
                        __builtin_amdgcn_ds_bpermute(c * 4, __builtin_bit_cast(int, d4[0])));
            p += b4v;
            if (net == 0) sv[sf] = p; else tv[sf] = p;
        }

        if (net == 1) {   // coupling update after both nets done
#pragma unroll
            for (int sf = 0; sf < SF; ++sf) {
                const float e2 = __expf(2.f * sv[sf]);
                const float s = 1.f - 2.f / (e2 + 1.f);      // tanh(sv)
                const float es = __expf(s);
                if (act) y0[sf] = fmaf(y0[sf], es, tv[sf]);
                else     y1[sf] = fmaf(y1[sf], es, tv[sf]);
                ld[sf] += s;
            }
        }
    }

    if (g == 0 && live) {   // 4 lane-groups hold identical results; group 0 writes
#pragma unroll
        for (int sf = 0; sf < SF; ++sf) {
            const long sid = base + 16 * sf + c;
            reinterpret_cast<float2*>(out)[sid] = make_float2(y0[sf], y1[sf]);
            out[2 * (long)n + sid] = ld[sf];
        }
    }
}

extern "C" void kernel_launch(void* const* d_in, const int* in_sizes, int n_in,
                              void* d_out, int out_size, void* d_ws, size_t ws_size,
                              hipStream_t stream) {
    const float* x = (const float*)d_in[0];
    float* ws = (float*)d_ws;

    prepack_kernel<<<16, PRE_NTH, 0, stream>>>(
        (const float*)d_in[1],  (const float*)d_in[2],  (const float*)d_in[3],
        (const float*)d_in[4],  (const float*)d_in[5],  (const float*)d_in[6],
        (const float*)d_in[7],  (const float*)d_in[8],  (const float*)d_in[9],
        (const float*)d_in[10], (const float*)d_in[11], (const float*)d_in[12],
        (const float*)d_in[13], (const float*)d_in[14], (const float*)d_in[15],
        (const float*)d_in[16], ws);

    const int n = in_sizes[0] / 2;                        // x is (N, 2)
    const int samples_per_block = (NTH / 64) * 16 * SF;   // 1024
    const int blocks = (n + samples_per_block - 1) / samples_per_block;

    nvp_mfma_kernel<<<blocks, NTH, 0, stream>>>(x, ws, (float*)d_out, n);
}

// Round 8
// 167.348 us; speedup vs baseline: 1.5501x; 1.2510x over previous
//
#include <hip/hip_runtime.h>
#include <hip/hip_fp16.h>
#include <math.h>

#define HID 64
#define NLAYERS 8
#define NTH 512        // 8 waves/block; 2 blocks/CU (LDS 48KB) -> 16 waves/CU
#define PRE_NTH 256
#define SF 8           // 16-sample fragments per wave => 128 samples/wave

// per-slot weight blob, ushort units (24576 B total, staged to LDS)
#define SLOT_US 12288
#define A1_US 0        // 2048 ushort
#define A2_US 2048     // 4096 ushort
#define A3_US 6144     // 4096 ushort
#define A4_US 10240    // 1024 ushort + 1024 pad
// float-unit offsets in ws
#define WS_BIAS_F 98304              // 16 slots * 6144 floats of blobs before this
#define WS_B4_F   (98304 + 16*3072)  // = 147456

typedef __attribute__((ext_vector_type(8))) _Float16 f16x8;
typedef __attribute__((ext_vector_type(2))) _Float16 f16x2;
typedef __attribute__((ext_vector_type(4))) float f32x4;

__device__ __forceinline__ unsigned short f2h(float f) {
    return __builtin_bit_cast(unsigned short, (_Float16)f);  // RNE scalar cvt
}

// f32 pair -> packed f16 (RTZ), one v_cvt_pkrtz_f16_f32
__device__ __forceinline__ f16x2 cvt2(float a, float b) {
    auto r = __builtin_amdgcn_cvt_pkrtz(a, b);
    return __builtin_bit_cast(f16x2, r);
}

// packed ReLU: one v_pk_max_f16 (relu∘cvt == cvt∘relu).
// __builtin_elementwise_max on the ext-vector avoids HIP's __hmax2 header
// (round-7 compile failure) and emits v_pk_max_f16 directly.
__device__ __forceinline__ f16x2 relu2(f16x2 x) {
    const f16x2 z = {(_Float16)0.f, (_Float16)0.f};
    return __builtin_elementwise_max(x, z);
}

// relu + f32->f16 pack: 6 VALU ops per 8 elems (was 12 in the bf16 path)
__device__ __forceinline__ f16x8 packR(f32x4 a, f32x4 b) {
    union { f16x2 h[4]; f16x8 v; } o;
    o.h[0] = relu2(cvt2(a[0], a[1]));
    o.h[1] = relu2(cvt2(a[2], a[3]));
    o.h[2] = relu2(cvt2(b[0], b[1]));
    o.h[3] = relu2(cvt2(b[2], b[3]));
    return o.v;
}

// DMA one 16B chunk per lane: global -> LDS (wave-uniform LDS base + lane*16).
__device__ __forceinline__ void gload16(const unsigned short* g, unsigned short* l) {
    __builtin_amdgcn_global_load_lds(
        (const __attribute__((address_space(1))) unsigned int*)g,
        (__attribute__((address_space(3))) unsigned int*)l, 16, 0, 0);
}

// Stage one 24576B slot blob: 8 waves x 3 rounds x 64 lanes x 16B.
__device__ __forceinline__ void stage(unsigned short* lds, const unsigned short* gsrc, int tid) {
    const int lane = tid & 63, wv = tid >> 6;
#pragma unroll
    for (int r = 0; r < 3; ++r) {
        const int chunk = r * 512 + wv * 64;             // in 16B units
        gload16(gsrc + (chunk + lane) * 8, lds + chunk * 8);
    }
}

// One block per (layer, net) slot. A-frag K-permutation
// k(ks,g,e)=16*(2ks+(e>>2))+4g+(e&3) makes layer n's D-layout directly
// consumable as layer n+1's B-operand. Weights stored as f16 bits.
__global__ void prepack_kernel(
    const float* __restrict__ s_w1, const float* __restrict__ s_b1,
    const float* __restrict__ s_w2, const float* __restrict__ s_b2,
    const float* __restrict__ s_w3, const float* __restrict__ s_b3,
    const float* __restrict__ s_w4, const float* __restrict__ s_b4,
    const float* __restrict__ t_w1, const float* __restrict__ t_b1,
    const float* __restrict__ t_w2, const float* __restrict__ t_b2,
    const float* __restrict__ t_w3, const float* __restrict__ t_b3,
    const float* __restrict__ t_w4, const float* __restrict__ t_b4,
    float* __restrict__ ws) {
    const int slot = blockIdx.x;            // l*2 + net
    const int l = slot >> 1, net = slot & 1;
    const int act = l & 1, pass = act ^ 1;
    const float* w1 = (net ? t_w1 : s_w1) + l * HID * 2;
    const float* b1 = (net ? t_b1 : s_b1) + l * HID;
    const float* w2 = (net ? t_w2 : s_w2) + l * HID * HID;
    const float* b2 = (net ? t_b2 : s_b2) + l * HID;
    const float* w3 = (net ? t_w3 : s_w3) + l * HID * HID;
    const float* b3 = (net ? t_b3 : s_b3) + l * HID;
    const float* w4 = (net ? t_w4 : s_w4) + l * 2 * HID;
    const float* b4 = (net ? t_b4 : s_b4) + l * 2;

    unsigned short* blob = reinterpret_cast<unsigned short*>(ws) + slot * SLOT_US;

    // A1: rank-1 layer-1 fragments (only k_phys==0 nonzero -> e==0, g==0)
    for (int idx = threadIdx.x; idx < 2048; idx += PRE_NTH) {
        const int e = idx & 7, lane = (idx >> 3) & 63, mf = idx >> 9;
        const int j = 16 * mf + (lane & 15);
        blob[A1_US + idx] = f2h((e == 0 && (lane >> 4) == 0) ? w1[2 * j + act] : 0.f);
    }
    // A2 / A3: 64x64 matmul fragments
    for (int mat = 0; mat < 2; ++mat) {
        const float* W = mat ? w3 : w2;
        unsigned short* dst = blob + (mat ? A3_US : A2_US);
        for (int idx = threadIdx.x; idx < 4096; idx += PRE_NTH) {
            const int e = idx & 7, lane = (idx >> 3) & 63, fr = idx >> 9;
            const int ks = fr & 1, mf = fr >> 1;
            const int j = 16 * mf + (lane & 15);
            const int k = 16 * (2 * ks + (e >> 2)) + 4 * (lane >> 4) + (e & 3);
            dst[idx] = f2h(W[j * HID + k]);
        }
    }
    // A4: W4 passive row in A row 0, rows 1..15 zero
    for (int idx = threadIdx.x; idx < 1024; idx += PRE_NTH) {
        const int e = idx & 7, lane = (idx >> 3) & 63, ks = idx >> 9;
        const int k = 16 * (2 * ks + (e >> 2)) + 4 * (lane >> 4) + (e & 3);
        blob[A4_US + idx] = f2h(((lane & 15) == 0) ? w4[pass * HID + k] : 0.f);
    }
    // biases b1,b2,b3 in D-fragment order (f32), kept in global (small)
    float* BP = ws + WS_BIAS_F + slot * 3072;
    for (int which = 0; which < 3; ++which) {
        const float* B = (which == 0) ? b1 : (which == 1) ? b2 : b3;
        for (int idx = threadIdx.x; idx < 1024; idx += PRE_NTH) {
            const int r = idx & 3, lane = (idx >> 2) & 63, f = idx >> 8;
            const int j = 16 * f + 4 * (lane >> 4) + r;
            BP[which * 1024 + idx] = B[j];
        }
    }
    if (threadIdx.x == 0) ws[WS_B4_F + slot] = b4[pass];
}

__global__ __launch_bounds__(NTH) void nvp_mfma_kernel(
    const float* __restrict__ x, const float* __restrict__ ws,
    float* __restrict__ out, int n) {
    __shared__ __align__(16) unsigned short smem[2 * SLOT_US];  // 48 KB double buffer
    const int tid = threadIdx.x;
    const int lane = tid & 63, wv = tid >> 6;
    const int c = lane & 15, g = lane >> 4;
    const int wid = blockIdx.x * (NTH / 64) + wv;
    long base = (long)wid * (16 * SF);
    const bool live = base < n;
    if (!live) base = 0;   // keep barrier participation uniform; skip writes later

    const unsigned short* wsu = reinterpret_cast<const unsigned short*>(ws);

    float y0[SF], y1[SF], ld[SF];
#pragma unroll
    for (int sf = 0; sf < SF; ++sf) {
        const float2 xv = reinterpret_cast<const float2*>(x)[base + 16 * sf + c];
        y0[sf] = xv.x; y1[sf] = xv.y; ld[sf] = 0.f;
    }

    // prologue: stage slot 0
    stage(smem, wsu, tid);

    float sv[SF], tv[SF];
    _Float16 xs[SF];

    for (int slot = 0; slot < 2 * NLAYERS; ++slot) {
        const int net = slot & 1;
        const int act = (slot >> 1) & 1;

        // staged data for this slot is ready after this barrier (vmcnt drained);
        // also closes all waves' reads of the buffer we stage into below.
        __syncthreads();
        if (slot < 2 * NLAYERS - 1)
            stage(smem + ((slot + 1) & 1) * SLOT_US, wsu + (slot + 1) * SLOT_US, tid);

        const unsigned short* SB = smem + (slot & 1) * SLOT_US;
        const float* BP = ws + WS_BIAS_F + slot * 3072;

        if (net == 0) {   // both nets consume the same active input (RNE cast)
#pragma unroll
            for (int sf = 0; sf < SF; ++sf) {
                const float xa = act ? y1[sf] : y0[sf];
                xs[sf] = (_Float16)xa;
            }
        }

        // ---- phase A weights: A1 (LDS), b1, b2 (global), A2 (LDS) ----
        f16x8 a1[4], a2[8];
        f32x4 c1v[4], c2v[4];
#pragma unroll
        for (int mf = 0; mf < 4; ++mf) {
            a1[mf] = *reinterpret_cast<const f16x8*>(SB + A1_US + (mf * 64 + lane) * 8);
            c1v[mf] = *reinterpret_cast<const f32x4*>(BP + 0 * 1024 + (mf * 64 + lane) * 4);
            c2v[mf] = *reinterpret_cast<const f32x4*>(BP + 1 * 1024 + (mf * 64 + lane) * 4);
        }
#pragma unroll
        for (int fr = 0; fr < 8; ++fr)
            a2[fr] = *reinterpret_cast<const f16x8*>(SB + A2_US + (fr * 64 + lane) * 8);

        f16x8 bfr[SF][2];
#pragma unroll
        for (int sf = 0; sf < SF; ++sf) {
            // B1 frag: f16(xa) at k_phys==0 (element 0, lanes g==0), zeros elsewhere
            f16x8 b1f = {0, 0, 0, 0, 0, 0, 0, 0};
            b1f[0] = (g == 0) ? xs[sf] : (_Float16)0.f;
            f32x4 acc[4];
            // layer 1: rank-1 MFMA, bias as C-in
#pragma unroll
            for (int mf = 0; mf < 4; ++mf)
                acc[mf] = __builtin_amdgcn_mfma_f32_16x16x32_f16(a1[mf], b1f, c1v[mf], 0, 0, 0);
            f16x8 bb0 = packR(acc[0], acc[1]);
            f16x8 bb1 = packR(acc[2], acc[3]);
            // layer 2
#pragma unroll
            for (int mf = 0; mf < 4; ++mf) {
                f32x4 t0 = __builtin_amdgcn_mfma_f32_16x16x32_f16(a2[2 * mf + 0], bb0, c2v[mf], 0, 0, 0);
                acc[mf]  = __builtin_amdgcn_mfma_f32_16x16x32_f16(a2[2 * mf + 1], bb1, t0, 0, 0, 0);
            }
            bfr[sf][0] = packR(acc[0], acc[1]);
            bfr[sf][1] = packR(acc[2], acc[3]);
        }

        // ---- phase B weights: A3 (LDS), b3 (global), A4 (LDS), b4 ----
        f16x8 a3[8], a4[2];
        f32x4 c3v[4];
#pragma unroll
        for (int fr = 0; fr < 8; ++fr)
            a3[fr] = *reinterpret_cast<const f16x8*>(SB + A3_US + (fr * 64 + lane) * 8);
#pragma unroll
        for (int mf = 0; mf < 4; ++mf)
            c3v[mf] = *reinterpret_cast<const f32x4*>(BP + 2 * 1024 + (mf * 64 + lane) * 4);
        a4[0] = *reinterpret_cast<const f16x8*>(SB + A4_US + (0 * 64 + lane) * 8);
        a4[1] = *reinterpret_cast<const f16x8*>(SB + A4_US + (1 * 64 + lane) * 8);
        const float b4v = ws[WS_B4_F + slot];

#pragma unroll
        for (int sf = 0; sf < SF; ++sf) {
            f32x4 acc[4];
            // layer 3
#pragma unroll
            for (int mf = 0; mf < 4; ++mf) {
                f32x4 t0 = __builtin_amdgcn_mfma_f32_16x16x32_f16(a3[2 * mf + 0], bfr[sf][0], c3v[mf], 0, 0, 0);
                acc[mf]  = __builtin_amdgcn_mfma_f32_16x16x32_f16(a3[2 * mf + 1], bfr[sf][1], t0, 0, 0, 0);
            }
            f16x8 bb0 = packR(acc[0], acc[1]);
            f16x8 bb1 = packR(acc[2], acc[3]);
            // layer 4: W4 row dot via MFMA row 0, then broadcast from lane c
            f32x4 z = {0.f, 0.f, 0.f, 0.f};
            f32x4 d4 = __builtin_amdgcn_mfma_f32_16x16x32_f16(a4[0], bb0, z, 0, 0, 0);
            d4 = __builtin_amdgcn_mfma_f32_16x16x32_f16(a4[1], bb1, d4, 0, 0, 0);
            float p = __builtin_bit_cast(float,
                        __builtin_amdgcn_ds_bpermute(c * 4, __builtin_bit_cast(int, d4[0])));
            p += b4v;
            if (net == 0) sv[sf] = p; else tv[sf] = p;
        }

        if (net == 1) {   // coupling update after both nets done
#pragma unroll
            for (int sf = 0; sf < SF; ++sf) {
                const float e2 = __expf(2.f * sv[sf]);
                const float s = 1.f - 2.f / (e2 + 1.f);      // tanh(sv)
                const float es = __expf(s);
                if (act) y0[sf] = fmaf(y0[sf], es, tv[sf]);
                else     y1[sf] = fmaf(y1[sf], es, tv[sf]);
                ld[sf] += s;
            }
        }
    }

    if (g == 0 && live) {   // 4 lane-groups hold identical results; group 0 writes
#pragma unroll
        for (int sf = 0; sf < SF; ++sf) {
            const long sid = base + 16 * sf + c;
            reinterpret_cast<float2*>(out)[sid] = make_float2(y0[sf], y1[sf]);
            out[2 * (long)n + sid] = ld[sf];
        }
    }
}

extern "C" void kernel_launch(void* const* d_in, const int* in_sizes, int n_in,
                              void* d_out, int out_size, void* d_ws, size_t ws_size,
                              hipStream_t stream) {
    const float* x = (const float*)d_in[0];
    float* ws = (float*)d_ws;

    prepack_kernel<<<16, PRE_NTH, 0, stream>>>(
        (const float*)d_in[1],  (const float*)d_in[2],  (const float*)d_in[3],
        (const float*)d_in[4],  (const float*)d_in[5],  (const float*)d_in[6],
        (const float*)d_in[7],  (const float*)d_in[8],  (const float*)d_in[9],
        (const float*)d_in[10], (const float*)d_in[11], (const float*)d_in[12],
        (const float*)d_in[13], (const float*)d_in[14], (const float*)d_in[15],
        (const float*)d_in[16], ws);

    const int n = in_sizes[0] / 2;                        // x is (N, 2)
    const int samples_per_block = (NTH / 64) * 16 * SF;   // 1024
    const int blocks = (n + samples_per_block - 1) / samples_per_block;

    nvp_mfma_kernel<<<blocks, NTH, 0, stream>>>(x, ws, (float*)d_out, n);
}